// Round 5
// baseline (395.618 us; speedup 1.0000x reference)
//
#include <hip/hip_runtime.h>
#include <hip/hip_bf16.h>

typedef unsigned short u16;
typedef unsigned int u32;

constexpr int kHW  = 16384;   // 128*128
constexpr int kC   = 192;
constexpr int kC3  = 576;
constexpr int kHD  = 48;
constexpr int kB   = 8;
constexpr int kSCH = 16;      // S-partial chunks (1024 n each)

typedef __attribute__((ext_vector_type(8))) short bfx8;  // 8 bf16 in 4 VGPRs
typedef __attribute__((ext_vector_type(4))) float fx4;

__device__ __forceinline__ float bfu2f(u32 u) { return __uint_as_float(u << 16); }
__device__ __forceinline__ u16 f2bfu(float f) {
  u32 x = __float_as_uint(f);
  return (u16)((x + 0x7fffu + ((x >> 16) & 1u)) >> 16);  // RNE
}
__device__ __forceinline__ u32 pack2(float a, float b) {
  union { __hip_bfloat162 h; u32 u; } cv;
  cv.h = __float22bfloat162_rn(make_float2(a, b));  // v_cvt_pk_bf16_f32
  return cv.u;
}

// ---------------------------------------------------------------------------
// P1: f32 -> bf16 cast (for w_qkv)
// ---------------------------------------------------------------------------
__global__ __launch_bounds__(256) void cast_f32_bf16(
    const float* __restrict__ in, u16* __restrict__ out, int n) {
  int i = blockIdx.x * 256 + threadIdx.x;
  if (i < n) out[i] = f2bfu(in[i]);
}

// ---------------------------------------------------------------------------
// K1/K5: MFMA GEMM with B consumed directly from [k][n] layout.
// Out[b][o][n] = sum_k A[b?][o][k] * B[b][k][n], K = 192.
// Block tile 64o x 256n, 4 waves (wave tile 64o x 64n).
// B staged global->LDS with in-LDS transpose: each thread loads a k-quad
// (4 rows, same n), packs k-contiguous uint2, writes swizzled Bs[n][k].
// Swizzle: byte(n,k) = n*128 + (((k>>3) ^ (n&7))*16) + (k&7)*2.
//   - staging writes: 64 lanes x 8B spread over all 32 banks, 4-deep = min.
//   - ds_read_b128 frags: 8 slots x 4 banks, 8-deep = min. Conflict-free.
// Grid: 1-D, o innermost + XCD swizzle -> o-blocks sharing a B tile run on
// the same XCD, so B is fetched ~once per tile.
// ---------------------------------------------------------------------------
template <bool IN_F32, bool OUT_BF16>
__global__ __launch_bounds__(256) void gemm_kn(
    const u16* __restrict__ Abase, long aStride,
    const void* __restrict__ Bbase, long bStride,
    void* __restrict__ OutBase, long oStride, int nOB) {
  const int wg = ((int)blockIdx.x & 7) * ((int)gridDim.x >> 3) + ((int)blockIdx.x >> 3);
  const int o0 = (wg % nOB) * 64;
  const int rest = wg / nOB;
  const int n0 = (rest & 63) * 256;
  const int b  = rest >> 6;

  const int t = threadIdx.x;
  const int lane = t & 63, wv = t >> 6;
  const int fr = lane & 15, fg = lane >> 4;
  const int lo5 = lane & 31, hi = lane >> 5;

  __shared__ u16 As[64 * 64];    // [o][k] swizzled, 8 KB
  __shared__ u16 Bs[256 * 64];   // [n][k] swizzled, 32 KB

  const u16* A = Abase + (size_t)b * aStride;

  fx4 acc[4][4];
#pragma unroll
  for (int m = 0; m < 4; ++m)
#pragma unroll
    for (int n = 0; n < 4; ++n) acc[m][n] = (fx4){0.f, 0.f, 0.f, 0.f};

  for (int k0 = 0; k0 < kC; k0 += 64) {
    if (k0) __syncthreads();
    // stage A tile (64 o x 64 k)
#pragma unroll
    for (int i = 0; i < 2; ++i) {
      int idx = t + i * 256;
      int row = idx >> 3, sl = idx & 7;
      uint4 v = *(const uint4*)(A + (size_t)(o0 + row) * kC + k0 + sl * 8);
      *(uint4*)(As + row * 64 + ((sl ^ (row & 7)) * 8)) = v;
    }
    // stage B tile (64 k x 256 n) transposed into Bs[n][k]
    if constexpr (IN_F32) {
      const float* Bg = (const float*)Bbase + (size_t)b * bStride;
#pragma unroll
      for (int i = 0; i < 16; ++i) {
        int p = wv * 16 + i;
        int cb = (p & 7) * 8, nb = (p >> 3) * 32;
        int kk = cb + hi * 4;
        int nn = nb + lo5;
        const float* src = Bg + (size_t)(k0 + kk) * kHW + n0 + nn;
        float d0 = src[0 * (size_t)kHW], d1 = src[1 * (size_t)kHW];
        float d2 = src[2 * (size_t)kHW], d3 = src[3 * (size_t)kHW];
        *(uint2*)(Bs + nn * 64 + (((kk >> 3) ^ (nn & 7)) * 8) + (kk & 7)) =
            make_uint2(pack2(d0, d1), pack2(d2, d3));
      }
    } else {
      const u16* Bg = (const u16*)Bbase + (size_t)b * bStride;
#pragma unroll
      for (int i = 0; i < 8; ++i) {
        int p = wv * 8 + i;
        int cb = (p & 7) * 8, nb = (p >> 3) * 64;
        int kk = cb + hi * 4;
        int nn = nb + lo5 * 2;
        const u16* src = Bg + (size_t)(k0 + kk) * kHW + n0 + nn;
        u32 d0 = *(const u32*)(src + 0 * (size_t)kHW);
        u32 d1 = *(const u32*)(src + 1 * (size_t)kHW);
        u32 d2 = *(const u32*)(src + 2 * (size_t)kHW);
        u32 d3 = *(const u32*)(src + 3 * (size_t)kHW);
        // repack to k-contiguous for n (lo halves) and n+1 (hi halves)
        u32 e0 = (d0 & 0xffffu) | (d1 << 16);
        u32 e1 = (d2 & 0xffffu) | (d3 << 16);
        u32 f0 = (d0 >> 16) | (d1 & 0xffff0000u);
        u32 f1 = (d2 >> 16) | (d3 & 0xffff0000u);
        *(uint2*)(Bs + nn * 64 + (((kk >> 3) ^ (nn & 7)) * 8) + (kk & 7)) = make_uint2(e0, e1);
        int nn1 = nn + 1;
        *(uint2*)(Bs + nn1 * 64 + (((kk >> 3) ^ (nn1 & 7)) * 8) + (kk & 7)) = make_uint2(f0, f1);
      }
    }
    __syncthreads();
#pragma unroll
    for (int ks = 0; ks < 2; ++ks) {
      bfx8 af[4], bf[4];
#pragma unroll
      for (int m = 0; m < 4; ++m) {
        int row = m * 16 + fr;
        af[m] = *(const bfx8*)(As + row * 64 + (((ks * 4 + fg) ^ (row & 7)) * 8));
      }
#pragma unroll
      for (int n = 0; n < 4; ++n) {
        int row = wv * 64 + n * 16 + fr;
        bf[n] = *(const bfx8*)(Bs + row * 64 + (((ks * 4 + fg) ^ (row & 7)) * 8));
      }
#pragma unroll
      for (int m = 0; m < 4; ++m)
#pragma unroll
        for (int n = 0; n < 4; ++n)
          acc[m][n] = __builtin_amdgcn_mfma_f32_16x16x32_bf16(af[m], bf[n], acc[m][n], 0, 0, 0);
    }
  }

  if constexpr (OUT_BF16) {
    u16* O = (u16*)OutBase + (size_t)b * oStride;
#pragma unroll
    for (int m = 0; m < 4; ++m)
#pragma unroll
      for (int n = 0; n < 4; ++n) {
        int col = n0 + wv * 64 + n * 16 + fr;
#pragma unroll
        for (int r = 0; r < 4; ++r)
          O[(size_t)(o0 + m * 16 + fg * 4 + r) * kHW + col] = f2bfu(acc[m][n][r]);
      }
  } else {
    float* O = (float*)OutBase + (size_t)b * oStride;
#pragma unroll
    for (int m = 0; m < 4; ++m)
#pragma unroll
      for (int n = 0; n < 4; ++n) {
        int col = n0 + wv * 64 + n * 16 + fr;
#pragma unroll
        for (int r = 0; r < 4; ++r)
          O[(size_t)(o0 + m * 16 + fg * 4 + r) * kHW + col] = acc[m][n][r];
      }
  }
}

// ---------------------------------------------------------------------------
// K2: depthwise 3x3, 4 output rows x 8 cols per thread, rolling row window.
// Also emits per-(plane,half) sum-of-squares partials for q,k channels.
// ---------------------------------------------------------------------------
__device__ __forceinline__ void load_row(const u16* __restrict__ plane, int hh,
                                         int w8, float v[10]) {
  if ((unsigned)hh > 127u) {
#pragma unroll
    for (int j = 0; j < 10; ++j) v[j] = 0.f;
    return;
  }
  const u16* row = plane + hh * 128 + w8 * 8;
  uint4 m = *(const uint4*)row;
  v[1] = bfu2f(m.x & 0xffffu); v[2] = bfu2f(m.x >> 16);
  v[3] = bfu2f(m.y & 0xffffu); v[4] = bfu2f(m.y >> 16);
  v[5] = bfu2f(m.z & 0xffffu); v[6] = bfu2f(m.z >> 16);
  v[7] = bfu2f(m.w & 0xffffu); v[8] = bfu2f(m.w >> 16);
  v[0] = (w8 > 0)  ? bfu2f(row[-1]) : 0.f;
  v[9] = (w8 < 15) ? bfu2f(row[8])  : 0.f;
}

__global__ __launch_bounds__(256) void dwconv3x3_v2(
    const u16* __restrict__ in, const float* __restrict__ wdw,
    u16* __restrict__ out, float* __restrict__ ssqp) {
  const int bc = blockIdx.x >> 1;       // plane index b*576+ch
  const int half = blockIdx.x & 1;
  const int t = threadIdx.x;
  const int w8 = t & 15;
  const int h0 = (half * 16 + (t >> 4)) * 4;
  const u16* p = in + (size_t)bc * kHW;
  const int ch = bc % kC3;
  float wt[9];
#pragma unroll
  for (int j = 0; j < 9; ++j) wt[j] = wdw[ch * 9 + j];

  float v[3][10];
  load_row(p, h0 - 1, w8, v[0]);
  load_row(p, h0,     w8, v[1]);
  float ssq = 0.f;
  u16* op = out + (size_t)bc * kHW + h0 * 128 + w8 * 8;
#pragma unroll
  for (int r = 0; r < 4; ++r) {
    load_row(p, h0 + r + 1, w8, v[(r + 2) % 3]);
    const float* r0 = v[r % 3];
    const float* r1 = v[(r + 1) % 3];
    const float* r2 = v[(r + 2) % 3];
    float o[8];
#pragma unroll
    for (int j = 0; j < 8; ++j) {
      o[j] = wt[0] * r0[j] + wt[1] * r0[j + 1] + wt[2] * r0[j + 2]
           + wt[3] * r1[j] + wt[4] * r1[j + 1] + wt[5] * r1[j + 2]
           + wt[6] * r2[j] + wt[7] * r2[j + 1] + wt[8] * r2[j + 2];
      ssq += o[j] * o[j];
    }
    *(uint4*)(op + r * 128) = make_uint4(pack2(o[0], o[1]), pack2(o[2], o[3]),
                                         pack2(o[4], o[5]), pack2(o[6], o[7]));
  }
  if (ch < 2 * kC) {  // q,k channels: block-uniform branch
#pragma unroll
    for (int d = 1; d < 64; d <<= 1) ssq += __shfl_xor(ssq, d);
    __shared__ float red[4];
    if ((t & 63) == 0) red[t >> 6] = ssq;
    __syncthreads();
    if (t == 0) ssqp[bc * 2 + half] = red[0] + red[1] + red[2] + red[3];
  }
}

// ---------------------------------------------------------------------------
// K3: LDS-staged MFMA split-K of S = q k^T. Block = (chunk of 1024 n, bh).
// ---------------------------------------------------------------------------
__global__ __launch_bounds__(256) void qk_mfma_lds(
    const u16* __restrict__ qkv2, float* __restrict__ Spart) {
  const int chunk = blockIdx.x;   // 0..15
  const int bh = blockIdx.y;      // 0..31
  const int b = bh >> 2, hh = bh & 3;
  const u16* qp = qkv2 + (size_t)(b * kC3 + hh * kHD) * kHW;
  const u16* kp = qp + (size_t)kC * kHW;

  __shared__ u16 smem[24576];     // 48 KB: qs | ks; sred aliases
  u16* qs = smem;
  u16* ks = smem + 12288;
  float* sred = (float*)smem;

  const int t = threadIdx.x;
  const int wv = t >> 6, lane = t & 63;
  const int fr = lane & 15, fg = lane >> 4;

  fx4 acc[3][3];
#pragma unroll
  for (int i = 0; i < 3; ++i)
#pragma unroll
    for (int j = 0; j < 3; ++j) acc[i][j] = (fx4){0.f, 0.f, 0.f, 0.f};

  for (int round = 0; round < 4; ++round) {
    if (round) __syncthreads();
    const int nb = chunk * 1024 + round * 256;
#pragma unroll
    for (int j = 0; j < 6; ++j) {   // 1536 uint4 per operand
      int idx = t + j * 256;
      int c = idx >> 5, sl = idx & 31;
      *(uint4*)(qs + c * 256 + ((sl ^ (c & 31)) * 8)) =
          *(const uint4*)(qp + (size_t)c * kHW + nb + sl * 8);
      *(uint4*)(ks + c * 256 + ((sl ^ (c & 31)) * 8)) =
          *(const uint4*)(kp + (size_t)c * kHW + nb + sl * 8);
    }
    __syncthreads();
#pragma unroll
    for (int s = 0; s < 2; ++s) {
      const int slot = wv * 8 + s * 4 + fg;
      bfx8 aq[3], ak[3];
#pragma unroll
      for (int tt = 0; tt < 3; ++tt) {
        int c = tt * 16 + fr;
        aq[tt] = *(const bfx8*)(qs + c * 256 + ((slot ^ (c & 31)) * 8));
        ak[tt] = *(const bfx8*)(ks + c * 256 + ((slot ^ (c & 31)) * 8));
      }
#pragma unroll
      for (int i = 0; i < 3; ++i)
#pragma unroll
        for (int j = 0; j < 3; ++j)
          acc[i][j] = __builtin_amdgcn_mfma_f32_16x16x32_bf16(aq[i], ak[j], acc[i][j], 0, 0, 0);
    }
  }

  __syncthreads();                 // tile reads done; reuse LDS for reduce
  float* my = sred + wv * 2400;
#pragma unroll
  for (int i = 0; i < 3; ++i)
#pragma unroll
    for (int j = 0; j < 3; ++j)
#pragma unroll
      for (int r = 0; r < 4; ++r)
        my[(i * 16 + fg * 4 + r) * 50 + j * 16 + fr] = acc[i][j][r];
  __syncthreads();
  float* Sp = Spart + ((size_t)chunk * 32 + bh) * (kHD * kHD);
  for (int p = t; p < kHD * kHD; p += 256) {
    int idx = (p / kHD) * 50 + (p % kHD);
    Sp[p] = sred[idx] + sred[2400 + idx] + sred[4800 + idx] + sred[7200 + idx];
  }
}

// ---------------------------------------------------------------------------
// K3b: reduce partials, fold norms (eps=1e-12) + temperature, row softmax.
// ---------------------------------------------------------------------------
__global__ __launch_bounds__(256) void attn_softmax(
    const float* __restrict__ Spart, const float* __restrict__ ssqp,
    const float* __restrict__ temp, float* __restrict__ attn) {
  const int bh = blockIdx.x, b = bh >> 2, hh = bh & 3;
  const int t = threadIdx.x;
  __shared__ float S[kHD * kHD];
  __shared__ float qn[kHD], kinv[kHD];
  for (int p = t; p < kHD * kHD; p += 256) {
    float s = 0.f;
#pragma unroll
    for (int c = 0; c < kSCH; ++c) s += Spart[((size_t)c * 32 + bh) * (kHD * kHD) + p];
    S[p] = s;
  }
  if (t < 48) {
    int pc = b * kC3 + hh * kHD + t;                 // q channel plane
    qn[t] = sqrtf(ssqp[pc * 2] + ssqp[pc * 2 + 1]);
  } else if (t < 96) {
    int pc = b * kC3 + kC + hh * kHD + (t - 48);     // k channel plane
    kinv[t - 48] = 1.f / fmaxf(sqrtf(ssqp[pc * 2] + ssqp[pc * 2 + 1]), 1e-12f);
  }
  __syncthreads();
  if (t < 48) {
    const float T = temp[hh];
    const float sqr = T / fmaxf(qn[t], 1e-12f);
    float m = -3.4e38f;
    for (int d = 0; d < kHD; ++d) {
      float v = S[t * kHD + d] * sqr * kinv[d];
      S[t * kHD + d] = v;
      m = fmaxf(m, v);
    }
    float sum = 0.f;
    for (int d = 0; d < kHD; ++d) {
      float e = expf(S[t * kHD + d] - m);
      S[t * kHD + d] = e;
      sum += e;
    }
    const float inv = 1.f / sum;
    float* A = attn + (size_t)bh * (kHD * kHD) + t * kHD;
    for (int d = 0; d < kHD; ++d) A[d] = S[t * kHD + d] * inv;
  }
}

// ---------------------------------------------------------------------------
// K4: M[b][o][j=hh*48+d] = sum_c w_out[o][hh*48+c] * attn[b,hh,c,d]  (bf16)
// ---------------------------------------------------------------------------
__global__ __launch_bounds__(256) void make_m(
    const float* __restrict__ wout, const float* __restrict__ attn, u16* __restrict__ M) {
  int g = blockIdx.x * 256 + threadIdx.x;
  if (g >= kB * kC * kC) return;
  int j = g % kC;
  int o = (g / kC) % kC;
  int b = g / (kC * kC);
  int hh = j / kHD, d = j % kHD;
  const float* A = attn + (size_t)(b * 4 + hh) * (kHD * kHD) + d;
  const float* wo = wout + (size_t)o * kC + hh * kHD;
  float s = 0.f;
#pragma unroll
  for (int c = 0; c < kHD; ++c) s += wo[c] * A[c * kHD];
  M[g] = f2bfu(s);
}

// ---------------------------------------------------------------------------
extern "C" void kernel_launch(void* const* d_in, const int* in_sizes, int n_in,
                              void* d_out, int out_size, void* d_ws, size_t ws_size,
                              hipStream_t stream) {
  const float* x    = (const float*)d_in[0];
  const float* wqkv = (const float*)d_in[1];
  const float* wdw  = (const float*)d_in[2];
  const float* temp = (const float*)d_in[3];
  const float* wout = (const float*)d_in[4];

  size_t off = 0;
  u16* qkv1 = (u16*)((char*)d_ws + off); off += (size_t)kB * kC3 * kHW * 2;  // 151 MB
  u16* qkv2 = (u16*)((char*)d_ws + off); off += (size_t)kB * kC3 * kHW * 2;  // 151 MB
  u16* Wq   = (u16*)((char*)d_ws + off); off += (size_t)kC3 * kC * 2;
  float* ssqp = (float*)((char*)d_ws + off); off += (size_t)kB * kC3 * 2 * 4; // 37 KB
  if (off > ws_size) return;  // insufficient workspace -> fail visibly

  // attention scratch aliases qkv1 (dead after dwconv)
  float* Spart = (float*)qkv1;                              // 16*32*2304*4 = 4.7 MB
  float* attnb = Spart + (size_t)kSCH * 32 * kHD * kHD;
  u16*   Mb    = (u16*)(attnb + (size_t)32 * kHD * kHD);

  // P1: weight cast
  cast_f32_bf16<<<dim3((kC3 * kC + 255) / 256), 256, 0, stream>>>(wqkv, Wq, kC3 * kC);
  // K1: qkv1 = Wq @ x (MFMA, f32 B consumed directly, bf16 out)
  gemm_kn<true, true><<<dim3((kC3 / 64) * 64 * kB), 256, 0, stream>>>(
      Wq, 0L, (const void*)x, (long)kC * kHW, (void*)qkv1, (long)kC3 * kHW, kC3 / 64);
  // K2: depthwise 3x3 (+ q,k sumsq partials)
  dwconv3x3_v2<<<dim3(kB * kC3 * 2), 256, 0, stream>>>(qkv1, wdw, qkv2, ssqp);
  // K3: S partials (LDS-staged MFMA)
  qk_mfma_lds<<<dim3(kSCH, 32), 256, 0, stream>>>(qkv2, Spart);
  // K3b: reduce + normalize + softmax
  attn_softmax<<<dim3(32), 256, 0, stream>>>(Spart, ssqp, temp, attnb);
  // K4: M = w_out folded through attn (bf16)
  make_m<<<dim3((kB * kC * kC + 255) / 256), 256, 0, stream>>>(wout, attnb, Mb);
  // K5: out = M @ v (MFMA, bf16 B consumed directly from qkv2, f32 out)
  gemm_kn<false, false><<<dim3((kC / 64) * 64 * kB), 256, 0, stream>>>(
      Mb, (long)kC * kC, (const void*)(qkv2 + (size_t)2 * kC * kHW),
      (long)kC3 * kHW, d_out, (long)kC * kHW, kC / 64);
}

// Round 6
// 268.744 us; speedup vs baseline: 1.4721x; 1.4721x over previous
//
#include <hip/hip_runtime.h>
#include <hip/hip_bf16.h>

typedef unsigned short u16;
typedef unsigned int u32;

constexpr int kHW  = 16384;   // 128*128
constexpr int kC   = 192;
constexpr int kC3  = 576;
constexpr int kHD  = 48;
constexpr int kB   = 8;
constexpr int kSCH = 16;      // S-partial chunks (1024 n each)

typedef __attribute__((ext_vector_type(8))) short bfx8;  // 8 bf16 in 4 VGPRs
typedef __attribute__((ext_vector_type(4))) float fx4;

__device__ __forceinline__ float bfu2f(u32 u) { return __uint_as_float(u << 16); }
__device__ __forceinline__ u16 f2bfu(float f) {
  u32 x = __float_as_uint(f);
  return (u16)((x + 0x7fffu + ((x >> 16) & 1u)) >> 16);  // RNE
}
__device__ __forceinline__ u32 pack2(float a, float b) {
  union { __hip_bfloat162 h; u32 u; } cv;
  cv.h = __float22bfloat162_rn(make_float2(a, b));  // v_cvt_pk_bf16_f32
  return cv.u;
}

// ---------------------------------------------------------------------------
// P1: f32 -> bf16 cast (for w_qkv)
// ---------------------------------------------------------------------------
__global__ __launch_bounds__(256) void cast_f32_bf16(
    const float* __restrict__ in, u16* __restrict__ out, int n) {
  int i = blockIdx.x * 256 + threadIdx.x;
  if (i < n) out[i] = f2bfu(in[i]);
}

// ---------------------------------------------------------------------------
// P2: x [b][192][16384] f32 -> xT [b][16384][192] bf16
// ---------------------------------------------------------------------------
__global__ __launch_bounds__(256) void transpose_cast_x(
    const float* __restrict__ X, u16* __restrict__ XT) {
  const int n0 = blockIdx.x * 64, c0 = blockIdx.y * 64, b = blockIdx.z;
  const float* xp = X + (size_t)b * kC * kHW;
  u16* xtp = XT + (size_t)b * kHW * kC;
  __shared__ u16 tile[64][84];
  const int t = threadIdx.x;
#pragma unroll
  for (int i = 0; i < 4; ++i) {
    int idx = t + i * 256;                 // 1024 float4 = 64c x 64n
    int c = idx >> 4, n4 = (idx & 15) * 4;
    float4 v = *(const float4*)(xp + (size_t)(c0 + c) * kHW + n0 + n4);
    *(uint2*)(&tile[c][n4]) = make_uint2(pack2(v.x, v.y), pack2(v.z, v.w));
  }
  __syncthreads();
  const int r = t & 63, ch = (t >> 6) * 16;   // ch wave-uniform -> 2-way reads
  u32 w[8];
#pragma unroll
  for (int j = 0; j < 8; ++j)
    w[j] = (u32)tile[ch + 2 * j][r] | ((u32)tile[ch + 2 * j + 1][r] << 16);
  u16* dst = xtp + (size_t)(n0 + r) * kC + c0 + ch;
  *(uint4*)dst       = make_uint4(w[0], w[1], w[2], w[3]);
  *(uint4*)(dst + 8) = make_uint4(w[4], w[5], w[6], w[7]);
}

// ---------------------------------------------------------------------------
// K2b: v [b][c][n] bf16 -> vT [b][n][c] bf16
// ---------------------------------------------------------------------------
__global__ __launch_bounds__(256) void transpose_bf16(
    const u16* __restrict__ V, long srcBatch, u16* __restrict__ VT, long dstBatch) {
  const int n0 = blockIdx.x * 64, c0 = blockIdx.y * 64, b = blockIdx.z;
  const u16* vp = V + (size_t)b * srcBatch;
  u16* vtp = VT + (size_t)b * dstBatch;
  __shared__ u16 tile[64][84];
  const int t = threadIdx.x;
#pragma unroll
  for (int i = 0; i < 2; ++i) {
    int idx = t + i * 256;                 // 512 uint4 = 64c x 64n
    int c = idx >> 3, n8 = (idx & 7) * 8;
    *(uint4*)(&tile[c][n8]) = *(const uint4*)(vp + (size_t)(c0 + c) * kHW + n0 + n8);
  }
  __syncthreads();
  const int r = t & 63, ch = (t >> 6) * 16;
  u32 w[8];
#pragma unroll
  for (int j = 0; j < 8; ++j)
    w[j] = (u32)tile[ch + 2 * j][r] | ((u32)tile[ch + 2 * j + 1][r] << 16);
  u16* dst = vtp + (size_t)(n0 + r) * kC + c0 + ch;
  *(uint4*)dst       = make_uint4(w[0], w[1], w[2], w[3]);
  *(uint4*)(dst + 8) = make_uint4(w[4], w[5], w[6], w[7]);
}

// ---------------------------------------------------------------------------
// K1/K5: MFMA GEMM. Out[b][o][n] = A[b?] @ BT[b][n][k], K=192.
// Grid: 1-D linearized (o-block innermost) + bijective XCD swizzle so all
// o-blocks sharing a B-tile run on the same XCD -> B fetched ~once per XCD.
// Requires gridDim.x % 8 == 0 (4608 and 1536: both OK).
// ---------------------------------------------------------------------------
template <bool OUT_BF16>
__global__ __launch_bounds__(256) void gemm_mfma(
    const u16* __restrict__ Abase, long aStride,
    const u16* __restrict__ Bbase, long bStride,
    void* __restrict__ OutBase, long oStride, int nOB) {
  const int nwg = (int)gridDim.x;
  const int wg = ((int)blockIdx.x & 7) * (nwg >> 3) + ((int)blockIdx.x >> 3);
  const int o0 = (wg % nOB) * 64;
  const int rest = wg / nOB;
  const int n0 = (rest & 63) * 256;
  const int b  = rest >> 6;

  const int t = threadIdx.x;
  const int lane = t & 63, wv = t >> 6;
  const int fr = lane & 15, fg = lane >> 4;

  __shared__ u16 As[64 * 64];
  __shared__ u16 Bs[256 * 64];

  const u16* A  = Abase + (size_t)b * aStride;
  const u16* Bp = Bbase + (size_t)b * bStride;

  fx4 acc[4][4];
#pragma unroll
  for (int m = 0; m < 4; ++m)
#pragma unroll
    for (int n = 0; n < 4; ++n) acc[m][n] = (fx4){0.f, 0.f, 0.f, 0.f};

  for (int k0 = 0; k0 < kC; k0 += 64) {
    if (k0) __syncthreads();
#pragma unroll
    for (int i = 0; i < 2; ++i) {
      int idx = t + i * 256;
      int row = idx >> 3, sl = idx & 7;
      uint4 v = *(const uint4*)(A + (size_t)(o0 + row) * kC + k0 + sl * 8);
      *(uint4*)(As + row * 64 + ((sl ^ (row & 7)) * 8)) = v;
    }
#pragma unroll
    for (int i = 0; i < 8; ++i) {
      int idx = t + i * 256;
      int row = idx >> 3, sl = idx & 7;
      uint4 v = *(const uint4*)(Bp + (size_t)(n0 + row) * kC + k0 + sl * 8);
      *(uint4*)(Bs + row * 64 + ((sl ^ (row & 7)) * 8)) = v;
    }
    __syncthreads();
#pragma unroll
    for (int ks = 0; ks < 2; ++ks) {
      bfx8 af[4], bf[4];
#pragma unroll
      for (int m = 0; m < 4; ++m) {
        int row = m * 16 + fr;
        af[m] = *(const bfx8*)(As + row * 64 + (((ks * 4 + fg) ^ (row & 7)) * 8));
      }
#pragma unroll
      for (int n = 0; n < 4; ++n) {
        int row = wv * 64 + n * 16 + fr;
        bf[n] = *(const bfx8*)(Bs + row * 64 + (((ks * 4 + fg) ^ (row & 7)) * 8));
      }
#pragma unroll
      for (int m = 0; m < 4; ++m)
#pragma unroll
        for (int n = 0; n < 4; ++n)
          acc[m][n] = __builtin_amdgcn_mfma_f32_16x16x32_bf16(af[m], bf[n], acc[m][n], 0, 0, 0);
    }
  }

  if constexpr (OUT_BF16) {
    u16* O = (u16*)OutBase + (size_t)b * oStride;
#pragma unroll
    for (int m = 0; m < 4; ++m)
#pragma unroll
      for (int n = 0; n < 4; ++n) {
        int col = n0 + wv * 64 + n * 16 + fr;
#pragma unroll
        for (int r = 0; r < 4; ++r)
          O[(size_t)(o0 + m * 16 + fg * 4 + r) * kHW + col] = f2bfu(acc[m][n][r]);
      }
  } else {
    float* O = (float*)OutBase + (size_t)b * oStride;
#pragma unroll
    for (int m = 0; m < 4; ++m)
#pragma unroll
      for (int n = 0; n < 4; ++n) {
        int col = n0 + wv * 64 + n * 16 + fr;
#pragma unroll
        for (int r = 0; r < 4; ++r)
          O[(size_t)(o0 + m * 16 + fg * 4 + r) * kHW + col] = acc[m][n][r];
      }
  }
}

// ---------------------------------------------------------------------------
// K2: depthwise 3x3, 4 output rows x 8 cols per thread, rolling row window.
// Also emits per-(plane,half) sum-of-squares partials for q,k channels.
// ---------------------------------------------------------------------------
__device__ __forceinline__ void load_row(const u16* __restrict__ plane, int hh,
                                         int w8, float v[10]) {
  if ((unsigned)hh > 127u) {
#pragma unroll
    for (int j = 0; j < 10; ++j) v[j] = 0.f;
    return;
  }
  const u16* row = plane + hh * 128 + w8 * 8;
  uint4 m = *(const uint4*)row;
  v[1] = bfu2f(m.x & 0xffffu); v[2] = bfu2f(m.x >> 16);
  v[3] = bfu2f(m.y & 0xffffu); v[4] = bfu2f(m.y >> 16);
  v[5] = bfu2f(m.z & 0xffffu); v[6] = bfu2f(m.z >> 16);
  v[7] = bfu2f(m.w & 0xffffu); v[8] = bfu2f(m.w >> 16);
  v[0] = (w8 > 0)  ? bfu2f(row[-1]) : 0.f;
  v[9] = (w8 < 15) ? bfu2f(row[8])  : 0.f;
}

__global__ __launch_bounds__(256) void dwconv3x3_v2(
    const u16* __restrict__ in, const float* __restrict__ wdw,
    u16* __restrict__ out, float* __restrict__ ssqp) {
  const int bc = blockIdx.x >> 1;       // plane index b*576+ch
  const int half = blockIdx.x & 1;
  const int t = threadIdx.x;
  const int w8 = t & 15;
  const int h0 = (half * 16 + (t >> 4)) * 4;
  const u16* p = in + (size_t)bc * kHW;
  const int ch = bc % kC3;
  float wt[9];
#pragma unroll
  for (int j = 0; j < 9; ++j) wt[j] = wdw[ch * 9 + j];

  float v[3][10];
  load_row(p, h0 - 1, w8, v[0]);
  load_row(p, h0,     w8, v[1]);
  float ssq = 0.f;
  u16* op = out + (size_t)bc * kHW + h0 * 128 + w8 * 8;
#pragma unroll
  for (int r = 0; r < 4; ++r) {
    load_row(p, h0 + r + 1, w8, v[(r + 2) % 3]);
    const float* r0 = v[r % 3];
    const float* r1 = v[(r + 1) % 3];
    const float* r2 = v[(r + 2) % 3];
    float o[8];
#pragma unroll
    for (int j = 0; j < 8; ++j) {
      o[j] = wt[0] * r0[j] + wt[1] * r0[j + 1] + wt[2] * r0[j + 2]
           + wt[3] * r1[j] + wt[4] * r1[j + 1] + wt[5] * r1[j + 2]
           + wt[6] * r2[j] + wt[7] * r2[j + 1] + wt[8] * r2[j + 2];
      ssq += o[j] * o[j];
    }
    *(uint4*)(op + r * 128) = make_uint4(pack2(o[0], o[1]), pack2(o[2], o[3]),
                                         pack2(o[4], o[5]), pack2(o[6], o[7]));
  }
  if (ch < 2 * kC) {  // q,k channels: block-uniform branch
#pragma unroll
    for (int d = 1; d < 64; d <<= 1) ssq += __shfl_xor(ssq, d);
    __shared__ float red[4];
    if ((t & 63) == 0) red[t >> 6] = ssq;
    __syncthreads();
    if (t == 0) ssqp[bc * 2 + half] = red[0] + red[1] + red[2] + red[3];
  }
}

// ---------------------------------------------------------------------------
// K3: LDS-staged MFMA split-K of S = q k^T. Block = (chunk of 1024 n, bh).
// ---------------------------------------------------------------------------
__global__ __launch_bounds__(256) void qk_mfma_lds(
    const u16* __restrict__ qkv2, float* __restrict__ Spart) {
  const int chunk = blockIdx.x;   // 0..15
  const int bh = blockIdx.y;      // 0..31
  const int b = bh >> 2, hh = bh & 3;
  const u16* qp = qkv2 + (size_t)(b * kC3 + hh * kHD) * kHW;
  const u16* kp = qp + (size_t)kC * kHW;

  __shared__ u16 smem[24576];     // 48 KB: qs | ks; sred aliases
  u16* qs = smem;
  u16* ks = smem + 12288;
  float* sred = (float*)smem;

  const int t = threadIdx.x;
  const int wv = t >> 6, lane = t & 63;
  const int fr = lane & 15, fg = lane >> 4;

  fx4 acc[3][3];
#pragma unroll
  for (int i = 0; i < 3; ++i)
#pragma unroll
    for (int j = 0; j < 3; ++j) acc[i][j] = (fx4){0.f, 0.f, 0.f, 0.f};

  for (int round = 0; round < 4; ++round) {
    if (round) __syncthreads();
    const int nb = chunk * 1024 + round * 256;
#pragma unroll
    for (int j = 0; j < 6; ++j) {   // 1536 uint4 per operand
      int idx = t + j * 256;
      int c = idx >> 5, sl = idx & 31;
      *(uint4*)(qs + c * 256 + ((sl ^ (c & 31)) * 8)) =
          *(const uint4*)(qp + (size_t)c * kHW + nb + sl * 8);
      *(uint4*)(ks + c * 256 + ((sl ^ (c & 31)) * 8)) =
          *(const uint4*)(kp + (size_t)c * kHW + nb + sl * 8);
    }
    __syncthreads();
#pragma unroll
    for (int s = 0; s < 2; ++s) {
      const int slot = wv * 8 + s * 4 + fg;
      bfx8 aq[3], ak[3];
#pragma unroll
      for (int tt = 0; tt < 3; ++tt) {
        int c = tt * 16 + fr;
        aq[tt] = *(const bfx8*)(qs + c * 256 + ((slot ^ (c & 31)) * 8));
        ak[tt] = *(const bfx8*)(ks + c * 256 + ((slot ^ (c & 31)) * 8));
      }
#pragma unroll
      for (int i = 0; i < 3; ++i)
#pragma unroll
        for (int j = 0; j < 3; ++j)
          acc[i][j] = __builtin_amdgcn_mfma_f32_16x16x32_bf16(aq[i], ak[j], acc[i][j], 0, 0, 0);
    }
  }

  __syncthreads();                 // tile reads done; reuse LDS for reduce
  float* my = sred + wv * 2400;
#pragma unroll
  for (int i = 0; i < 3; ++i)
#pragma unroll
    for (int j = 0; j < 3; ++j)
#pragma unroll
      for (int r = 0; r < 4; ++r)
        my[(i * 16 + fg * 4 + r) * 50 + j * 16 + fr] = acc[i][j][r];
  __syncthreads();
  float* Sp = Spart + ((size_t)chunk * 32 + bh) * (kHD * kHD);
  for (int p = t; p < kHD * kHD; p += 256) {
    int idx = (p / kHD) * 50 + (p % kHD);
    Sp[p] = sred[idx] + sred[2400 + idx] + sred[4800 + idx] + sred[7200 + idx];
  }
}

// ---------------------------------------------------------------------------
// K3b: reduce partials, fold norms (eps=1e-12) + temperature, row softmax.
// ---------------------------------------------------------------------------
__global__ __launch_bounds__(256) void attn_softmax(
    const float* __restrict__ Spart, const float* __restrict__ ssqp,
    const float* __restrict__ temp, float* __restrict__ attn) {
  const int bh = blockIdx.x, b = bh >> 2, hh = bh & 3;
  const int t = threadIdx.x;
  __shared__ float S[kHD * kHD];
  __shared__ float qn[kHD], kinv[kHD];
  for (int p = t; p < kHD * kHD; p += 256) {
    float s = 0.f;
#pragma unroll
    for (int c = 0; c < kSCH; ++c) s += Spart[((size_t)c * 32 + bh) * (kHD * kHD) + p];
    S[p] = s;
  }
  if (t < 48) {
    int pc = b * kC3 + hh * kHD + t;                 // q channel plane
    qn[t] = sqrtf(ssqp[pc * 2] + ssqp[pc * 2 + 1]);
  } else if (t < 96) {
    int pc = b * kC3 + kC + hh * kHD + (t - 48);     // k channel plane
    kinv[t - 48] = 1.f / fmaxf(sqrtf(ssqp[pc * 2] + ssqp[pc * 2 + 1]), 1e-12f);
  }
  __syncthreads();
  if (t < 48) {
    const float T = temp[hh];
    const float sqr = T / fmaxf(qn[t], 1e-12f);
    float m = -3.4e38f;
    for (int d = 0; d < kHD; ++d) {
      float v = S[t * kHD + d] * sqr * kinv[d];
      S[t * kHD + d] = v;
      m = fmaxf(m, v);
    }
    float sum = 0.f;
    for (int d = 0; d < kHD; ++d) {
      float e = expf(S[t * kHD + d] - m);
      S[t * kHD + d] = e;
      sum += e;
    }
    const float inv = 1.f / sum;
    float* A = attn + (size_t)bh * (kHD * kHD) + t * kHD;
    for (int d = 0; d < kHD; ++d) A[d] = S[t * kHD + d] * inv;
  }
}

// ---------------------------------------------------------------------------
// K4: M[b][o][j=hh*48+d] = sum_c w_out[o][hh*48+c] * attn[b,hh,c,d]  (bf16)
// ---------------------------------------------------------------------------
__global__ __launch_bounds__(256) void make_m(
    const float* __restrict__ wout, const float* __restrict__ attn, u16* __restrict__ M) {
  int g = blockIdx.x * 256 + threadIdx.x;
  if (g >= kB * kC * kC) return;
  int j = g % kC;
  int o = (g / kC) % kC;
  int b = g / (kC * kC);
  int hh = j / kHD, d = j % kHD;
  const float* A = attn + (size_t)(b * 4 + hh) * (kHD * kHD) + d;
  const float* wo = wout + (size_t)o * kC + hh * kHD;
  float s = 0.f;
#pragma unroll
  for (int c = 0; c < kHD; ++c) s += wo[c] * A[c * kHD];
  M[g] = f2bfu(s);
}

// ---------------------------------------------------------------------------
extern "C" void kernel_launch(void* const* d_in, const int* in_sizes, int n_in,
                              void* d_out, int out_size, void* d_ws, size_t ws_size,
                              hipStream_t stream) {
  const float* x    = (const float*)d_in[0];
  const float* wqkv = (const float*)d_in[1];
  const float* wdw  = (const float*)d_in[2];
  const float* temp = (const float*)d_in[3];
  const float* wout = (const float*)d_in[4];

  size_t off = 0;
  u16* qkv1 = (u16*)((char*)d_ws + off); off += (size_t)kB * kC3 * kHW * 2;  // 151 MB
  u16* qkv2 = (u16*)((char*)d_ws + off); off += (size_t)kB * kC3 * kHW * 2;  // 151 MB
  u16* xT   = (u16*)((char*)d_ws + off); off += (size_t)kB * kHW * kC * 2;   // 50 MB (xT, then vT)
  u16* Wq   = (u16*)((char*)d_ws + off); off += (size_t)kC3 * kC * 2;
  float* ssqp = (float*)((char*)d_ws + off); off += (size_t)kB * kC3 * 2 * 4; // 37 KB
  if (off > ws_size) return;  // insufficient workspace -> fail visibly
  u16* vT = xT;               // xT dead after K1

  // attention scratch aliases qkv1 (dead after dwconv)
  float* Spart = (float*)qkv1;                              // 16*32*2304*4 = 4.7 MB
  float* attnb = Spart + (size_t)kSCH * 32 * kHD * kHD;
  u16*   Mb    = (u16*)(attnb + (size_t)32 * kHD * kHD);

  // P1/P2: weight cast + x transpose-cast
  cast_f32_bf16<<<dim3((kC3 * kC + 255) / 256), 256, 0, stream>>>(wqkv, Wq, kC3 * kC);
  transpose_cast_x<<<dim3(kHW / 64, kC / 64, kB), 256, 0, stream>>>(x, xT);
  // K1: qkv1 = Wq @ x (MFMA, bf16 out); grid 9*64*8 = 4608 (%8==0)
  gemm_mfma<true><<<dim3((kC3 / 64) * 64 * kB), 256, 0, stream>>>(
      Wq, 0L, xT, (long)kHW * kC, (void*)qkv1, (long)kC3 * kHW, kC3 / 64);
  // K2: depthwise 3x3 (+ q,k sumsq partials)
  dwconv3x3_v2<<<dim3(kB * kC3 * 2), 256, 0, stream>>>(qkv1, wdw, qkv2, ssqp);
  // K2b: vT = transpose(v)
  transpose_bf16<<<dim3(kHW / 64, kC / 64, kB), 256, 0, stream>>>(
      qkv2 + (size_t)2 * kC * kHW, (long)kC3 * kHW, vT, (long)kHW * kC);
  // K3: S partials (LDS-staged MFMA)
  qk_mfma_lds<<<dim3(kSCH, 32), 256, 0, stream>>>(qkv2, Spart);
  // K3b: reduce + normalize + softmax
  attn_softmax<<<dim3(32), 256, 0, stream>>>(Spart, ssqp, temp, attnb);
  // K4: M = w_out folded through attn (bf16)
  make_m<<<dim3((kB * kC * kC + 255) / 256), 256, 0, stream>>>(wout, attnb, Mb);
  // K5: out = M @ v (MFMA, f32 out); grid 3*64*8 = 1536 (%8==0)
  gemm_mfma<false><<<dim3((kC / 64) * 64 * kB), 256, 0, stream>>>(
      Mb, (long)kC * kC, vT, (long)kHW * kC, d_out, (long)kC * kHW, kC / 64);
}